// Round 20
// baseline (218.649 us; speedup 1.0000x reference)
//
#include <hip/hip_runtime.h>
#include <math.h>

// DTM weighted-quantile kernel, v7b: 2-level 64-ary LDS histogram CDF.
// v7 FAILED (absmax 4.88): wave_scan_sum used row_mask 0xf on the bcast
// steps -- valid as a lane63 REDUCTION (v5/v6 only read lane63) but NOT as
// an inclusive scan (rows 2/3 double-count row 1). Fix: canonical LLVM
// AtomicOptimizer masks -- row_bcast:15 row_mask:0xa, row_bcast:31 row_mask:0xc.
// History: v1 82.4 / v2 79.5 / v3 90.9 / v4 120.6 / v5 74.0 / v6 93.9.
// Model: ~80% issue-bound; bisection rescans 2048 elems per bit; the
// histogram gains 6 bits per scan. 2 scans + ~10 round trips total.

#define M_POINTS 2048
#define PER_LANE 32  // M_POINTS / 64
#define M0 0.3f

// ---- DPP primitives (row_shr:N = 0x110|N, row_bcast:15 = 0x142, :31 = 0x143)
template<int CTRL, int RMASK = 0xf>
__device__ __forceinline__ float dpp_add_step(float x) {
    union { int i; float f; } u, r;
    u.f = x;
    r.i = __builtin_amdgcn_update_dpp(0, u.i, CTRL, RMASK, 0xf, true); // 0-fill
    return x + r.f;
}
template<int CTRL>
__device__ __forceinline__ float dpp_max_step(float x) {   // -inf fill
    union { int i; float f; } u, r;
    u.f = x;
    r.i = __builtin_amdgcn_update_dpp(0xFF800000, u.i, CTRL, 0xf, 0xf, false);
    return fmaxf(x, r.f);
}
template<int CTRL>
__device__ __forceinline__ float dpp_min_step(float x) {   // +inf fill
    union { int i; float f; } u, r;
    u.f = x;
    r.i = __builtin_amdgcn_update_dpp(0x7F800000, u.i, CTRL, 0xf, 0xf, false);
    return fminf(x, r.f);
}
__device__ __forceinline__ float lane63(float x) {
    union { int i; float f; } u;
    u.f = x;
    u.i = __builtin_amdgcn_readlane(u.i, 63);
    return u.f;
}
__device__ __forceinline__ float readlane_f(float x, int l) {
    union { int i; float f; } u;
    u.f = x;
    u.i = __builtin_amdgcn_readlane(u.i, l);   // l uniform (SGPR)
    return u.f;
}
// TRUE inclusive wave64 scan (LLVM AtomicOptimizer masks: 0xa then 0xc).
__device__ __forceinline__ float wave_scan_sum(float x) {
    x = dpp_add_step<0x111>(x);        // row_shr:1
    x = dpp_add_step<0x112>(x);        // row_shr:2
    x = dpp_add_step<0x114>(x);        // row_shr:4
    x = dpp_add_step<0x118>(x);        // row_shr:8   (per-row inclusive scan)
    x = dpp_add_step<0x142, 0xa>(x);   // row_bcast:15 -> rows 1,3 only
    x = dpp_add_step<0x143, 0xc>(x);   // row_bcast:31 -> rows 2,3 only
    return x;                          // lane i = sum lanes 0..i; lane63 = total
}
// Reduce-only variants (lane63 read) keep 0xf masks -- HW-proven in v5/v6.
__device__ __forceinline__ float wave_reduce_sum(float x) {
    x = dpp_add_step<0x111>(x); x = dpp_add_step<0x112>(x);
    x = dpp_add_step<0x114>(x); x = dpp_add_step<0x118>(x);
    x = dpp_add_step<0x142>(x); x = dpp_add_step<0x143>(x);
    return lane63(x);
}
__device__ __forceinline__ float wave_reduce_max(float x) {
    x = dpp_max_step<0x111>(x); x = dpp_max_step<0x112>(x);
    x = dpp_max_step<0x114>(x); x = dpp_max_step<0x118>(x);
    x = dpp_max_step<0x142>(x); x = dpp_max_step<0x143>(x);
    return lane63(x);
}
__device__ __forceinline__ float wave_reduce_min(float x) {
    x = dpp_min_step<0x111>(x); x = dpp_min_step<0x112>(x);
    x = dpp_min_step<0x114>(x); x = dpp_min_step<0x118>(x);
    x = dpp_min_step<0x142>(x); x = dpp_min_step<0x143>(x);
    return lane63(x);
}

__global__ __launch_bounds__(256) void dtm_kernel(
    const float* __restrict__ inputs,   // [B, M, 2]
    const float* __restrict__ weight,   // [B, M]
    const float* __restrict__ grid,     // [N, 2]
    float* __restrict__ out,            // [B, N]  (f32)
    int B, int N)
{
    __shared__ float hist[4 * 64];                 // per-wave private slices
    const int lane = threadIdx.x & 63;
    float* __restrict__ hb = &hist[(threadIdx.x >> 6) * 64];

    const int gwave = blockIdx.x * (blockDim.x >> 6) + (threadIdx.x >> 6);
    if (gwave >= B * N) return;           // wave-uniform exit
    const int b = gwave / N;
    const int n = gwave - b * N;

    const float gx = grid[2 * n];
    const float gy = grid[2 * n + 1];

    const float* __restrict__ inb = inputs + (size_t)b * M_POINTS * 2;
    const float* __restrict__ wb  = weight + (size_t)b * M_POINTS;

    // Contiguous 32 elements per lane -> float4 staging.
    const int base = lane * PER_LANE;
    const float4* __restrict__ xyv = reinterpret_cast<const float4*>(inb + 2 * base);
    const float4* __restrict__ wv  = reinterpret_cast<const float4*>(wb + base);

    float d2[PER_LANE], w[PER_LANE];
    float wsum_local = 0.0f, vmax_local = 0.0f;
    #pragma unroll
    for (int q = 0; q < PER_LANE / 4; ++q) {
        const float4 wq = wv[q];
        const float4 a  = xyv[2 * q];       // x0 y0 x1 y1
        const float4 c4 = xyv[2 * q + 1];   // x2 y2 x3 y3
        float dx, dy;
        dx = a.x  - gx; dy = a.y  - gy; d2[4*q+0] = fmaf(dx, dx, dy * dy);
        dx = a.z  - gx; dy = a.w  - gy; d2[4*q+1] = fmaf(dx, dx, dy * dy);
        dx = c4.x - gx; dy = c4.y - gy; d2[4*q+2] = fmaf(dx, dx, dy * dy);
        dx = c4.z - gx; dy = c4.w - gy; d2[4*q+3] = fmaf(dx, dx, dy * dy);
        w[4*q+0] = wq.x; w[4*q+1] = wq.y; w[4*q+2] = wq.z; w[4*q+3] = wq.w;
        wsum_local += wq.x + wq.y + wq.z + wq.w;
        vmax_local = fmaxf(vmax_local, fmaxf(fmaxf(d2[4*q+0], d2[4*q+1]),
                                             fmaxf(d2[4*q+2], d2[4*q+3])));
    }
    const float total = wave_reduce_sum(wsum_local);
    const float vmax  = wave_reduce_max(vmax_local);
    const float bound = M0 * total;

    const float vspan  = fmaxf(vmax, 1e-30f) * 1.0000002f;
    const float scale1 = 64.0f / vspan;

    // ---- Level-1 histogram (own slice; intra-wave DS ordering only).
    hb[lane] = 0.0f;
    __threadfence_block();
    #pragma unroll
    for (int j = 0; j < PER_LANE; ++j) {
        const int bi = min(63, (int)(d2[j] * scale1));
        atomicAdd(&hb[bi], w[j]);
    }
    __threadfence_block();
    const float pref1 = wave_scan_sum(hb[lane]);   // inclusive CDF at buckets
    const unsigned long long m1 = __ballot(pref1 >= bound);
    const int k = m1 ? (__ffsll((long long)m1) - 1) : 63;
    const float wlo1 = (k == 0) ? 0.0f : readlane_f(pref1, k - 1);

    // ---- Level-2 histogram within bucket k (64x finer).
    hb[lane] = 0.0f;
    __threadfence_block();
    #pragma unroll
    for (int j = 0; j < PER_LANE; ++j) {
        const float x = d2[j] * scale1;
        const int bi = min(63, (int)x);
        if (bi == k) {
            const int b2 = min(63, (int)((x - (float)k) * 64.0f));
            atomicAdd(&hb[b2], w[j]);
        }
    }
    __threadfence_block();
    const float pref2 = wave_scan_sum(hb[lane]);
    const unsigned long long m2 = __ballot(wlo1 + pref2 >= bound);
    const int k2 = m2 ? (__ffsll((long long)m2) - 1) : 63;
    float wlo = wlo1 + ((k2 == 0) ? 0.0f : readlane_f(pref2, k2 - 1));

    // ---- vlo = max d2 in the strictly-prior bucket set (exact value-set).
    float cand = -1.0f;
    #pragma unroll
    for (int j = 0; j < PER_LANE; ++j) {
        const float x = d2[j] * scale1;
        const int bi = min(63, (int)x);
        const int b2 = min(63, (int)((x - (float)k) * 64.0f));
        const bool prior = (bi < k) || (bi == k && b2 < k2);
        cand = prior ? fmaxf(cand, d2[j]) : cand;
    }
    float vlo = wave_reduce_max(cand);             // -1 if prior set empty

    // ---- Exact extraction (v5's, unchanged): ascending distinct values.
    float r2 = vmax, W = wlo;
    #pragma unroll 1
    for (int step = 0; step < 64; ++step) {
        float m = __builtin_inff();
        #pragma unroll
        for (int j = 0; j < PER_LANE; ++j)
            m = fminf(m, (d2[j] > vlo) ? d2[j] : __builtin_inff());
        m = wave_reduce_min(m);                    // smallest value > vlo
        float c = 0.0f;
        #pragma unroll
        for (int j = 0; j < PER_LANE; ++j)
            c += (d2[j] <= m) ? w[j] : 0.0f;
        c = wave_reduce_sum(c);
        if (c >= bound) { r2 = m; W = wlo; break; }  // wlo = cnt(values < m)
        vlo = m; wlo = c;
    }

    // ---- S = sum_{d2 < r2} w*d2.
    float S = 0.0f;
    #pragma unroll
    for (int j = 0; j < PER_LANE; ++j)
        if (d2[j] < r2) S = fmaf(w[j], d2[j], S);
    S = wave_reduce_sum(S);

    const float margin = fmaxf(bound - W, 0.0f);
    const float val = fmaxf(fmaf(r2, margin, S), 0.0f);
    if (lane == 0) out[gwave] = sqrtf(val / bound);
}

extern "C" void kernel_launch(void* const* d_in, const int* in_sizes, int n_in,
                              void* d_out, int out_size, void* d_ws, size_t ws_size,
                              hipStream_t stream) {
    const float* inputs = (const float*)d_in[0];   // [B, M, 2]
    const float* weight = (const float*)d_in[1];   // [B, M]
    const float* grid   = (const float*)d_in[2];   // [N, 2]
    float* out = (float*)d_out;                    // [B, N] f32

    const int N = in_sizes[2] / 2;                 // 6561
    const int B = out_size / N;                    // 2
    // M hard-wired to 2048 (PER_LANE*64).

    const int total_waves = B * N;                 // 13122
    const int waves_per_block = 256 / 64;
    const int blocks = (total_waves + waves_per_block - 1) / waves_per_block;

    dtm_kernel<<<blocks, 256, 0, stream>>>(inputs, weight, grid, out, B, N);
}

// Round 21
// 121.194 us; speedup vs baseline: 1.8041x; 1.8041x over previous
//
#include <hip/hip_runtime.h>
#include <math.h>

// DTM weighted-quantile kernel, v8: v5 (best, 74.0us) + verified warm-start.
// History: v1 82.4 / v2 79.5 / v3 90.9 / v4 120.6 / v5 74.0 / v6 93.9 /
// v7b 164.9 (LDS-atomic histogram: DS serialization, VALUBusy 19%).
// Occupancy insight (r20): 42% == 12.8 waves/SIMD == ENTIRE grid resident;
// TLP is maxed. Levers: total VALU work + serial chain count.
// v8 cuts ~1/3 of bisection passes via a warm-start probe at
// t0 = 0.75*weighted_mean(d2) whose bracket placement is VERIFIED by an
// exact count (invariant always holds; any guess is safe). Staging reduces
// (total / wd2 / max) are hand-interleaved into one overlapped DPP block.

#define M_POINTS 2048
#define PER_LANE 32  // M_POINTS / 64
#define M0 0.3f

// ---- DPP primitives (row_shr:N = 0x110|N, row_bcast:15 = 0x142, :31 = 0x143)
// Reduce-only (lane63) with full row_mask 0xf -- HW-proven in v5/v6 (absmax 0).
template<int CTRL>
__device__ __forceinline__ float dpp_add_step(float x) {
    union { int i; float f; } u, r;
    u.f = x;
    r.i = __builtin_amdgcn_update_dpp(0, u.i, CTRL, 0xf, 0xf, true); // 0-fill
    return x + r.f;
}
template<int CTRL>
__device__ __forceinline__ float dpp_max_step(float x) {   // valid for x >= 0
    union { int i; float f; } u, r;
    u.f = x;
    r.i = __builtin_amdgcn_update_dpp(0, u.i, CTRL, 0xf, 0xf, true);
    return fmaxf(x, r.f);
}
template<int CTRL>
__device__ __forceinline__ float dpp_min_step(float x) {   // +inf fill
    union { int i; float f; } u, r;
    u.f = x;
    r.i = __builtin_amdgcn_update_dpp(0x7F800000, u.i, CTRL, 0xf, 0xf, false);
    return fminf(x, r.f);
}
__device__ __forceinline__ float lane63(float x) {
    union { int i; float f; } u;
    u.f = x;
    u.i = __builtin_amdgcn_readlane(u.i, 63);
    return u.f;                                   // wave-uniform (SGPR)
}
__device__ __forceinline__ float wave_reduce_sum(float x) {
    x = dpp_add_step<0x111>(x); x = dpp_add_step<0x112>(x);
    x = dpp_add_step<0x114>(x); x = dpp_add_step<0x118>(x);
    x = dpp_add_step<0x142>(x); x = dpp_add_step<0x143>(x);
    return lane63(x);
}
__device__ __forceinline__ float wave_reduce_min(float x) {
    x = dpp_min_step<0x111>(x); x = dpp_min_step<0x112>(x);
    x = dpp_min_step<0x114>(x); x = dpp_min_step<0x118>(x);
    x = dpp_min_step<0x142>(x); x = dpp_min_step<0x143>(x);
    return lane63(x);
}
// Interleaved: two sums + one max, chains overlap (~ one chain latency).
__device__ __forceinline__ void wave_reduce_ssm(float& a, float& b, float& m) {
    a = dpp_add_step<0x111>(a); b = dpp_add_step<0x111>(b); m = dpp_max_step<0x111>(m);
    a = dpp_add_step<0x112>(a); b = dpp_add_step<0x112>(b); m = dpp_max_step<0x112>(m);
    a = dpp_add_step<0x114>(a); b = dpp_add_step<0x114>(b); m = dpp_max_step<0x114>(m);
    a = dpp_add_step<0x118>(a); b = dpp_add_step<0x118>(b); m = dpp_max_step<0x118>(m);
    a = dpp_add_step<0x142>(a); b = dpp_add_step<0x142>(b); m = dpp_max_step<0x142>(m);
    a = dpp_add_step<0x143>(a); b = dpp_add_step<0x143>(b); m = dpp_max_step<0x143>(m);
    a = lane63(a); b = lane63(b); m = lane63(m);
}

__global__ __launch_bounds__(256) void dtm_kernel(
    const float* __restrict__ inputs,   // [B, M, 2]
    const float* __restrict__ weight,   // [B, M]
    const float* __restrict__ grid,     // [N, 2]
    float* __restrict__ out,            // [B, N]  (f32)
    int B, int N)
{
    const int lane = threadIdx.x & 63;
    const int gwave = blockIdx.x * (blockDim.x >> 6) + (threadIdx.x >> 6);
    if (gwave >= B * N) return;           // wave-uniform exit
    const int b = gwave / N;
    const int n = gwave - b * N;

    const float gx = grid[2 * n];
    const float gy = grid[2 * n + 1];

    const float* __restrict__ inb = inputs + (size_t)b * M_POINTS * 2;
    const float* __restrict__ wb  = weight + (size_t)b * M_POINTS;

    // Contiguous 32 elements per lane -> float4 staging.
    const int base = lane * PER_LANE;
    const float4* __restrict__ xyv = reinterpret_cast<const float4*>(inb + 2 * base);
    const float4* __restrict__ wv  = reinterpret_cast<const float4*>(wb + base);

    float d2[PER_LANE], w[PER_LANE];
    float wsum_local = 0.0f, wd2_local = 0.0f, vmax_local = 0.0f;
    #pragma unroll
    for (int q = 0; q < PER_LANE / 4; ++q) {
        const float4 wq = wv[q];
        const float4 a  = xyv[2 * q];       // x0 y0 x1 y1
        const float4 c4 = xyv[2 * q + 1];   // x2 y2 x3 y3
        float dx, dy;
        dx = a.x  - gx; dy = a.y  - gy; d2[4*q+0] = fmaf(dx, dx, dy * dy);
        dx = a.z  - gx; dy = a.w  - gy; d2[4*q+1] = fmaf(dx, dx, dy * dy);
        dx = c4.x - gx; dy = c4.y - gy; d2[4*q+2] = fmaf(dx, dx, dy * dy);
        dx = c4.z - gx; dy = c4.w - gy; d2[4*q+3] = fmaf(dx, dx, dy * dy);
        w[4*q+0] = wq.x; w[4*q+1] = wq.y; w[4*q+2] = wq.z; w[4*q+3] = wq.w;
        wsum_local += wq.x + wq.y + wq.z + wq.w;
        wd2_local  = fmaf(wq.x, d2[4*q+0], wd2_local);
        wd2_local  = fmaf(wq.y, d2[4*q+1], wd2_local);
        wd2_local  = fmaf(wq.z, d2[4*q+2], wd2_local);
        wd2_local  = fmaf(wq.w, d2[4*q+3], wd2_local);
        vmax_local = fmaxf(vmax_local, fmaxf(fmaxf(d2[4*q+0], d2[4*q+1]),
                                             fmaxf(d2[4*q+2], d2[4*q+3])));
    }
    float total = wsum_local, wd2sum = wd2_local, vmax = vmax_local;
    wave_reduce_ssm(total, wd2sum, vmax);
    const float bound = M0 * total;

    // ---- Warm-start probe: t0 ~ 0.75 * weighted mean of d2 (r* is the 30%
    // weighted quantile ~ 0.36-0.6 x mean across grid positions). Placement
    // is verified by an exact count, so any t0 preserves the invariant.
    float vlo = 0.0f, wlo = 0.0f;
    float vhi = vmax, whi = total;
    {
        const float t0 = 0.75f * (wd2sum / total);
        if (t0 > 0.0f && t0 < vmax) {
            float c0 = 0.0f;
            #pragma unroll
            for (int j = 0; j < PER_LANE; ++j)
                c0 += (d2[j] <= t0) ? w[j] : 0.0f;
            c0 = wave_reduce_sum(c0);
            if (c0 >= bound) { vhi = t0; whi = c0; }
            else             { vlo = t0; wlo = c0; }
        }
    }

    // ---- Phase 1: value-space bisection (v5's, from the warmed bracket).
    #pragma unroll 1
    for (int it = 0; it < 48; ++it) {
        if (whi - wlo <= 0.75f) break;               // ~<=2 elements remain
        const float vmid = 0.5f * (vlo + vhi);
        if (!(vmid > vlo && vmid < vhi)) break;      // adjacent floats (ties)
        float c = 0.0f;
        #pragma unroll
        for (int j = 0; j < PER_LANE; ++j)
            c += (d2[j] <= vmid) ? w[j] : 0.0f;
        c = wave_reduce_sum(c);
        if (c >= bound) { vhi = vmid; whi = c; }
        else            { vlo = vmid; wlo = c; }     // scalar branch
    }

    // ---- Phase 2: exact extraction - ascending distinct values above vlo.
    float r2 = vhi, W = wlo;
    #pragma unroll 1
    for (int step = 0; step < 64; ++step) {
        float m = __builtin_inff();
        #pragma unroll
        for (int j = 0; j < PER_LANE; ++j)
            m = fminf(m, (d2[j] > vlo) ? d2[j] : __builtin_inff());
        m = wave_reduce_min(m);                      // smallest value > vlo
        float c = 0.0f;
        #pragma unroll
        for (int j = 0; j < PER_LANE; ++j)
            c += (d2[j] <= m) ? w[j] : 0.0f;
        c = wave_reduce_sum(c);
        if (c >= bound) { r2 = m; W = wlo; break; }  // wlo = cnt(values < m)
        vlo = m; wlo = c;
    }

    // ---- Phase 3: S = sum_{d2 < r2} w*d2.
    float S = 0.0f;
    #pragma unroll
    for (int j = 0; j < PER_LANE; ++j)
        if (d2[j] < r2) S = fmaf(w[j], d2[j], S);
    S = wave_reduce_sum(S);

    const float margin = fmaxf(bound - W, 0.0f);     // clamp FP-noise sign flip
    const float val = fmaxf(fmaf(r2, margin, S), 0.0f);
    if (lane == 0) out[gwave] = sqrtf(val / bound);
}

extern "C" void kernel_launch(void* const* d_in, const int* in_sizes, int n_in,
                              void* d_out, int out_size, void* d_ws, size_t ws_size,
                              hipStream_t stream) {
    const float* inputs = (const float*)d_in[0];   // [B, M, 2]
    const float* weight = (const float*)d_in[1];   // [B, M]
    const float* grid   = (const float*)d_in[2];   // [N, 2]
    float* out = (float*)d_out;                    // [B, N] f32

    const int N = in_sizes[2] / 2;                 // 6561
    const int B = out_size / N;                    // 2
    // M hard-wired to 2048 (PER_LANE*64).

    const int total_waves = B * N;                 // 13122
    const int waves_per_block = 256 / 64;
    const int blocks = (total_waves + waves_per_block - 1) / waves_per_block;

    dtm_kernel<<<blocks, 256, 0, stream>>>(inputs, weight, grid, out, B, N);
}